// Round 6
// baseline (1421.716 us; speedup 1.0000x reference)
//
#include <hip/hip_runtime.h>

// CRF Viterbi decode: B=64, T=1024, K=256.
// emissions [B,T,K] f32, transitions [K,K] f32 (prev->next). out [B,T] f32 tags.
//
// Path A (states 64MB + bp 16MB + maps 256KB + exits 4KB):
//   1. crf_forward_states : sequential over t, 64 blocks. NAMED-REG trans slice
//      (round-5 post-mortem: float4 arrays were living in scratch, VGPR=48).
//   2. crf_bp_matrix      : parallel argmax backpointers, NAMED-REG trans slice.
//   3. crf_seg_maps       : per (b,seg) chase all 256 candidates -> entry maps.
//   4. crf_compose        : final-state argmax + 16 map hops -> segment exits.
//   5. crf_emit           : re-chase, winner thread writes tags.
// Path B (states+bp): monolithic backtrack. Path C (states+Tt): serial backtrack.

#define CRF_B 64
#define CRF_T 1024
#define CRF_K 256
#define NSEG  16
#define SEGLEN 64

#define LD4(v, p, col) { \
    v.x = trans[(size_t)(p) * CRF_K + (col)]; \
    v.y = trans[(size_t)((p) + 1) * CRF_K + (col)]; \
    v.z = trans[(size_t)((p) + 2) * CRF_K + (col)]; \
    v.w = trans[(size_t)((p) + 3) * CRF_K + (col)]; }

// ---------------------------------------------------------------------------
// Forward: 1024 thr = 8 prev-groups x 128 cols; each thread: cols c, c+128 and
// 32 prevs. 64 trans floats in NAMED registers.
// ---------------------------------------------------------------------------

#define FWD_CHUNK(idx, ta, tb) { \
    float4 sv = sp[idx]; \
    m0 = fmaxf(m0, fmaxf(fmaxf(sv.x + ta.x, sv.y + ta.y), \
                         fmaxf(sv.z + ta.z, sv.w + ta.w))); \
    m1 = fmaxf(m1, fmaxf(fmaxf(sv.x + tb.x, sv.y + tb.y), \
                         fmaxf(sv.z + tb.z, sv.w + tb.w))); }

__global__ __launch_bounds__(1024, 4) void crf_forward_states(
    const float* __restrict__ em, const float* __restrict__ trans,
    float* __restrict__ states)
{
    const int b   = blockIdx.x;
    const int tid = threadIdx.x;
    const int g   = tid >> 7;      // prev group 0..7
    const int c   = tid & 127;     // columns c and c+128

    __shared__ __align__(16) float s_state[CRF_K];
    __shared__ float s_partial[8][CRF_K];

    const int pbase = g * 32;
    const int c2    = c + 128;

    float4 ta0, ta1, ta2, ta3, ta4, ta5, ta6, ta7;
    float4 tb0, tb1, tb2, tb3, tb4, tb5, tb6, tb7;
    LD4(ta0, pbase +  0, c)  LD4(ta1, pbase +  4, c)
    LD4(ta2, pbase +  8, c)  LD4(ta3, pbase + 12, c)
    LD4(ta4, pbase + 16, c)  LD4(ta5, pbase + 20, c)
    LD4(ta6, pbase + 24, c)  LD4(ta7, pbase + 28, c)
    LD4(tb0, pbase +  0, c2) LD4(tb1, pbase +  4, c2)
    LD4(tb2, pbase +  8, c2) LD4(tb3, pbase + 12, c2)
    LD4(tb4, pbase + 16, c2) LD4(tb5, pbase + 20, c2)
    LD4(tb6, pbase + 24, c2) LD4(tb7, pbase + 28, c2)

    const float* emb = em + (size_t)b * CRF_T * CRF_K;
    if (tid < CRF_K) {
        float v = emb[tid];
        s_state[tid] = v;
        states[(size_t)b * CRF_K + tid] = v;   // t = 0
    }
    float e_cur = 0.0f;
    if (tid < CRF_K) e_cur = emb[CRF_K + tid];     // emission for t = 1
    __syncthreads();

    for (int t = 1; t < CRF_T; ++t) {
        float e_next = 0.0f;
        if (tid < CRF_K && t + 1 < CRF_T)
            e_next = emb[(t + 1) * CRF_K + tid];   // prefetch next step

        float m0 = -INFINITY, m1 = -INFINITY;
        const float4* sp = (const float4*)(s_state + pbase);
        FWD_CHUNK(0, ta0, tb0) FWD_CHUNK(1, ta1, tb1)
        FWD_CHUNK(2, ta2, tb2) FWD_CHUNK(3, ta3, tb3)
        FWD_CHUNK(4, ta4, tb4) FWD_CHUNK(5, ta5, tb5)
        FWD_CHUNK(6, ta6, tb6) FWD_CHUNK(7, ta7, tb7)

        s_partial[g][c]  = m0;
        s_partial[g][c2] = m1;
        __syncthreads();
        if (tid < CRF_K) {
            float m = s_partial[0][tid];
#pragma unroll
            for (int j = 1; j < 8; ++j) m = fmaxf(m, s_partial[j][tid]);
            float v = m + e_cur;
            s_state[tid] = v;
            states[((size_t)t * CRF_B + b) * CRF_K + tid] = v;
        }
        __syncthreads();
        e_cur = e_next;
    }
}

// ---------------------------------------------------------------------------
// Backpointer matrix: 1024 blocks (b x 16 segs) x 1024 thr = 4 groups x 256
// cols, 64 prevs/group. Ascending strict-> scan = jnp.argmax first-index ties.
// NAMED-REG trans slice (64 floats).
// ---------------------------------------------------------------------------

#define BP_CHUNK(idx, tr, p) { \
    float4 sv = sp[idx]; \
    float x0 = sv.x + tr.x; if (x0 > best) { best = x0; arg = (p); } \
    float x1 = sv.y + tr.y; if (x1 > best) { best = x1; arg = (p) + 1; } \
    float x2 = sv.z + tr.z; if (x2 > best) { best = x2; arg = (p) + 2; } \
    float x3 = sv.w + tr.w; if (x3 > best) { best = x3; arg = (p) + 3; } }

__global__ __launch_bounds__(1024, 4) void crf_bp_matrix(
    const float* __restrict__ states, const float* __restrict__ trans,
    unsigned char* __restrict__ bp)
{
    const int b   = blockIdx.x >> 4;
    const int seg = blockIdx.x & 15;
    const int tid = threadIdx.x;
    const int g   = tid >> 8;      // 0..3
    const int k   = tid & 255;

    __shared__ __align__(16) float s_row[CRF_K];
    __shared__ float s_pv[4][CRF_K];
    __shared__ int   s_pi[4][CRF_K];

    const int pbase = g * 64;

    float4 tr0, tr1, tr2, tr3, tr4, tr5, tr6, tr7;
    float4 tr8, tr9, trA, trB, trC, trD, trE, trF;
    LD4(tr0, pbase +  0, k) LD4(tr1, pbase +  4, k)
    LD4(tr2, pbase +  8, k) LD4(tr3, pbase + 12, k)
    LD4(tr4, pbase + 16, k) LD4(tr5, pbase + 20, k)
    LD4(tr6, pbase + 24, k) LD4(tr7, pbase + 28, k)
    LD4(tr8, pbase + 32, k) LD4(tr9, pbase + 36, k)
    LD4(trA, pbase + 40, k) LD4(trB, pbase + 44, k)
    LD4(trC, pbase + 48, k) LD4(trD, pbase + 52, k)
    LD4(trE, pbase + 56, k) LD4(trF, pbase + 60, k)

    const int t_lo = seg * SEGLEN;
    const int t_hi = min(t_lo + SEGLEN, CRF_T - 1);   // bp rows 0..1022

    unsigned char* bpb = bp + (size_t)b * (CRF_T - 1) * CRF_K;

    for (int t1 = t_lo; t1 < t_hi; ++t1) {
        if (tid < CRF_K)
            s_row[tid] = states[((size_t)t1 * CRF_B + b) * CRF_K + tid];
        __syncthreads();

        float best = -INFINITY;
        int   arg  = pbase;
        const float4* sp = (const float4*)(s_row + pbase);
        BP_CHUNK( 0, tr0, pbase +  0) BP_CHUNK( 1, tr1, pbase +  4)
        BP_CHUNK( 2, tr2, pbase +  8) BP_CHUNK( 3, tr3, pbase + 12)
        BP_CHUNK( 4, tr4, pbase + 16) BP_CHUNK( 5, tr5, pbase + 20)
        BP_CHUNK( 6, tr6, pbase + 24) BP_CHUNK( 7, tr7, pbase + 28)
        BP_CHUNK( 8, tr8, pbase + 32) BP_CHUNK( 9, tr9, pbase + 36)
        BP_CHUNK(10, trA, pbase + 40) BP_CHUNK(11, trB, pbase + 44)
        BP_CHUNK(12, trC, pbase + 48) BP_CHUNK(13, trD, pbase + 52)
        BP_CHUNK(14, trE, pbase + 56) BP_CHUNK(15, trF, pbase + 60)

        s_pv[g][k] = best;
        s_pi[g][k] = arg;
        __syncthreads();
        if (tid < CRF_K) {
            float bv = s_pv[0][tid];
            int   ba = s_pi[0][tid];
#pragma unroll
            for (int j = 1; j < 4; ++j) {
                float v = s_pv[j][tid];
                if (v > bv) { bv = v; ba = s_pi[j][tid]; }
            }
            bpb[(size_t)t1 * CRF_K + tid] = (unsigned char)ba;
        }
        __syncthreads();
    }
}

// ---------------------------------------------------------------------------
// Parallel backtrack (proven round-5): seg_maps -> compose -> emit.
// ---------------------------------------------------------------------------

__global__ __launch_bounds__(256) void crf_seg_maps(
    const unsigned char* __restrict__ bp, unsigned char* __restrict__ maps)
{
    const int b   = blockIdx.x >> 4;
    const int s   = blockIdx.x & 15;
    const int tid = threadIdx.x;
    const int rows = (s == NSEG - 1) ? SEGLEN - 1 : SEGLEN;
    const int r0   = s * SEGLEN;

    __shared__ unsigned char lbp[SEGLEN][CRF_K];   // 16 KB

    const unsigned char* bpb = bp + (size_t)b * (CRF_T - 1) * CRF_K;
    const int nw = rows * 64;
    for (int w = tid; w < nw; w += 256) {
        const int r = w >> 6, cc = w & 63;
        ((unsigned int*)lbp[r])[cc] =
            ((const unsigned int*)(bpb + (size_t)(r0 + r) * CRF_K))[cc];
    }
    __syncthreads();

    int tag = tid;   // candidate tag at segment exit (t = r0 + rows)
    for (int j = rows - 1; j >= 0; --j) tag = lbp[j][tag];
    maps[((size_t)b * NSEG + s) * CRF_K + tid] = (unsigned char)tag;
}

__global__ __launch_bounds__(256) void crf_compose(
    const float* __restrict__ states, const unsigned char* __restrict__ maps,
    int* __restrict__ exits, float* __restrict__ out)
{
    const int b   = blockIdx.x;
    const int tid = threadIdx.x;

    __shared__ float s_wv[4];
    __shared__ int   s_wi[4];

    float v = states[((size_t)(CRF_T - 1) * CRF_B + b) * CRF_K + tid];
    int   i = tid;
#pragma unroll
    for (int off = 32; off >= 1; off >>= 1) {
        float ov = __shfl_xor(v, off, 64);
        int   oi = __shfl_xor(i, off, 64);
        if (ov > v || (ov == v && oi < i)) { v = ov; i = oi; }
    }
    const int lane = tid & 63, wv = tid >> 6;
    if (lane == 0) { s_wv[wv] = v; s_wi[wv] = i; }
    __syncthreads();
    if (tid == 0) {
        float bv = s_wv[0]; int bi = s_wi[0];
#pragma unroll
        for (int w = 1; w < 4; ++w)
            if (s_wv[w] > bv) { bv = s_wv[w]; bi = s_wi[w]; }
        out[(size_t)b * CRF_T + (CRF_T - 1)] = (float)bi;
        int E = bi;                       // tag at t=1023 (exit of seg 15)
        exits[b * NSEG + NSEG - 1] = E;
        const unsigned char* mb = maps + (size_t)b * NSEG * CRF_K;
        for (int s = NSEG - 1; s >= 1; --s) {
            E = mb[(size_t)s * CRF_K + E];   // tag at t = s*64
            exits[b * NSEG + s - 1] = E;     // exit tag of segment s-1
        }
    }
}

__global__ __launch_bounds__(256) void crf_emit(
    const unsigned char* __restrict__ bp, const int* __restrict__ exits,
    float* __restrict__ out)
{
    const int b   = blockIdx.x >> 4;
    const int s   = blockIdx.x & 15;
    const int tid = threadIdx.x;
    const int rows = (s == NSEG - 1) ? SEGLEN - 1 : SEGLEN;
    const int r0   = s * SEGLEN;

    __shared__ unsigned char lbp[SEGLEN][CRF_K];

    const unsigned char* bpb = bp + (size_t)b * (CRF_T - 1) * CRF_K;
    const int nw = rows * 64;
    for (int w = tid; w < nw; w += 256) {
        const int r = w >> 6, cc = w & 63;
        ((unsigned int*)lbp[r])[cc] =
            ((const unsigned int*)(bpb + (size_t)(r0 + r) * CRF_K))[cc];
    }
    __syncthreads();

    int tag = tid;
    const bool win = (tid == exits[b * NSEG + s]);
    for (int j = rows - 1; j >= 0; --j) {
        tag = lbp[j][tag];                           // tag @ t = r0 + j
        if (win) out[(size_t)b * CRF_T + r0 + j] = (float)tag;
    }
}

// ---------------------------------------------------------------------------
// Fallback B: monolithic backtrack (proven round-4).
// ---------------------------------------------------------------------------

__global__ __launch_bounds__(256) void crf_backtrack(
    const float* __restrict__ states, const unsigned char* __restrict__ bp,
    float* __restrict__ out)
{
    const int b   = blockIdx.x;
    const int tid = threadIdx.x;

    __shared__ unsigned char lbp[SEGLEN][CRF_K];
    __shared__ unsigned char lmap[NSEG][CRF_K];
    __shared__ int   s_E[NSEG];
    __shared__ float s_wv[4];
    __shared__ int   s_wi[4];

    const unsigned char* bpb = bp + (size_t)b * (CRF_T - 1) * CRF_K;

    for (int s = 0; s < NSEG; ++s) {
        const int rows = (s == NSEG - 1) ? SEGLEN - 1 : SEGLEN;
        const int r0   = s * SEGLEN;
        const int nw   = rows * 64;
        for (int w = tid; w < nw; w += 256) {
            const int r = w >> 6, cc = w & 63;
            ((unsigned int*)lbp[r])[cc] =
                ((const unsigned int*)(bpb + (size_t)(r0 + r) * CRF_K))[cc];
        }
        __syncthreads();
        int tag = tid;
        for (int j = rows - 1; j >= 0; --j) tag = lbp[j][tag];
        lmap[s][tid] = (unsigned char)tag;
        __syncthreads();
    }

    float v = states[((size_t)(CRF_T - 1) * CRF_B + b) * CRF_K + tid];
    int   i = tid;
#pragma unroll
    for (int off = 32; off >= 1; off >>= 1) {
        float ov = __shfl_xor(v, off, 64);
        int   oi = __shfl_xor(i, off, 64);
        if (ov > v || (ov == v && oi < i)) { v = ov; i = oi; }
    }
    const int lane = tid & 63, wv = tid >> 6;
    if (lane == 0) { s_wv[wv] = v; s_wi[wv] = i; }
    __syncthreads();
    if (tid == 0) {
        float bv = s_wv[0]; int bi = s_wi[0];
#pragma unroll
        for (int w = 1; w < 4; ++w)
            if (s_wv[w] > bv) { bv = s_wv[w]; bi = s_wi[w]; }
        out[(size_t)b * CRF_T + (CRF_T - 1)] = (float)bi;
        int E = bi;
        s_E[NSEG - 1] = E;
        for (int s = NSEG - 1; s >= 1; --s) { E = lmap[s][E]; s_E[s - 1] = E; }
    }
    __syncthreads();

    for (int s = 0; s < NSEG; ++s) {
        const int rows = (s == NSEG - 1) ? SEGLEN - 1 : SEGLEN;
        const int r0   = s * SEGLEN;
        const int nw   = rows * 64;
        for (int w = tid; w < nw; w += 256) {
            const int r = w >> 6, cc = w & 63;
            ((unsigned int*)lbp[r])[cc] =
                ((const unsigned int*)(bpb + (size_t)(r0 + r) * CRF_K))[cc];
        }
        __syncthreads();
        int tag = tid;
        const bool win = (tid == s_E[s]);
        for (int j = rows - 1; j >= 0; --j) {
            tag = lbp[j][tag];
            if (win) out[(size_t)b * CRF_T + r0 + j] = (float)tag;
        }
        __syncthreads();
    }
}

// ---------------------------------------------------------------------------
// Fallback C: serial backtrack (proven round-2).
// ---------------------------------------------------------------------------

__global__ void crf_transpose_trans(const float* __restrict__ trans,
                                    float* __restrict__ Tt)
{
    const int k = blockIdx.x;
    const int p = threadIdx.x;
    Tt[(size_t)k * CRF_K + p] = trans[(size_t)p * CRF_K + k];
}

__device__ __forceinline__ int wave_argmax(float v, int i)
{
#pragma unroll
    for (int off = 32; off >= 1; off >>= 1) {
        float ov = __shfl_xor(v, off, 64);
        int   oi = __shfl_xor(i, off, 64);
        if (ov > v || (ov == v && oi < i)) { v = ov; i = oi; }
    }
    return i;
}

__device__ __forceinline__ int step_argmax(float4 sv, float4 tv, int base)
{
    float s0 = sv.x + tv.x, s1 = sv.y + tv.y;
    float s2 = sv.z + tv.z, s3 = sv.w + tv.w;
    float nbv = s0; int nbi = base;
    if (s1 > nbv) { nbv = s1; nbi = base + 1; }
    if (s2 > nbv) { nbv = s2; nbi = base + 2; }
    if (s3 > nbv) { nbv = s3; nbi = base + 3; }
    return wave_argmax(nbv, nbi);
}

__global__ __launch_bounds__(64) void crf_backtrack_states(
    const float* __restrict__ states, const float* __restrict__ Tt,
    float* __restrict__ out)
{
    const int b    = blockIdx.x;
    const int lane = threadIdx.x;
    const int base = lane * 4;

    const float4* stb =
        (const float4*)(states + ((size_t)(CRF_T - 1) * CRF_B + b) * CRF_K);
    float4 v = stb[lane];
    float bv = v.x; int bi = base;
    if (v.y > bv) { bv = v.y; bi = base + 1; }
    if (v.z > bv) { bv = v.z; bi = base + 2; }
    if (v.w > bv) { bv = v.w; bi = base + 3; }
    int tag = wave_argmax(bv, bi);
    if (lane == 0) out[(size_t)b * CRF_T + (CRF_T - 1)] = (float)tag;

    float* ob = out + (size_t)b * CRF_T;
    int t = CRF_T - 1;
    for (; t >= 4; t -= 4) {
        float4 sv0 = ((const float4*)(states + ((size_t)(t - 1) * CRF_B + b) * CRF_K))[lane];
        float4 sv1 = ((const float4*)(states + ((size_t)(t - 2) * CRF_B + b) * CRF_K))[lane];
        float4 sv2 = ((const float4*)(states + ((size_t)(t - 3) * CRF_B + b) * CRF_K))[lane];
        float4 sv3 = ((const float4*)(states + ((size_t)(t - 4) * CRF_B + b) * CRF_K))[lane];

        float4 tv = ((const float4*)(Tt + (size_t)tag * CRF_K))[lane];
        tag = step_argmax(sv0, tv, base);
        if (lane == 0) ob[t - 1] = (float)tag;
        tv = ((const float4*)(Tt + (size_t)tag * CRF_K))[lane];
        tag = step_argmax(sv1, tv, base);
        if (lane == 0) ob[t - 2] = (float)tag;
        tv = ((const float4*)(Tt + (size_t)tag * CRF_K))[lane];
        tag = step_argmax(sv2, tv, base);
        if (lane == 0) ob[t - 3] = (float)tag;
        tv = ((const float4*)(Tt + (size_t)tag * CRF_K))[lane];
        tag = step_argmax(sv3, tv, base);
        if (lane == 0) ob[t - 4] = (float)tag;
    }
    for (; t >= 1; --t) {
        float4 sv = ((const float4*)(states + ((size_t)(t - 1) * CRF_B + b) * CRF_K))[lane];
        float4 tv = ((const float4*)(Tt + (size_t)tag * CRF_K))[lane];
        tag = step_argmax(sv, tv, base);
        if (lane == 0) ob[t - 1] = (float)tag;
    }
}

__global__ void crf_zero_out(float* __restrict__ out, int n)
{
    int i = blockIdx.x * blockDim.x + threadIdx.x;
    if (i < n) out[i] = 0.0f;
}

// ---------------------------------------------------------------------------

extern "C" void kernel_launch(void* const* d_in, const int* in_sizes, int n_in,
                              void* d_out, int out_size, void* d_ws, size_t ws_size,
                              hipStream_t stream) {
    (void)in_sizes; (void)n_in;
    const float* em    = (const float*)d_in[0];   // [B,T,K]
    const float* trans = (const float*)d_in[1];   // [K,K]
    float* out = (float*)d_out;                   // [B,T]

    const size_t states_bytes = (size_t)CRF_T * CRF_B * CRF_K * sizeof(float); // 64 MB
    const size_t bp_bytes     = (size_t)CRF_B * (CRF_T - 1) * CRF_K;           // ~16 MB
    const size_t maps_bytes   = (size_t)CRF_B * NSEG * CRF_K;                  // 256 KB
    const size_t exits_bytes  = (size_t)CRF_B * NSEG * sizeof(int);            // 4 KB
    const size_t tt_bytes     = (size_t)CRF_K * CRF_K * sizeof(float);         // 256 KB

    char* w = (char*)d_ws;
    if (ws_size >= states_bytes + bp_bytes + maps_bytes + exits_bytes) {
        float*         states = (float*)w;            w += states_bytes;
        unsigned char* bp     = (unsigned char*)w;    w += bp_bytes;
        unsigned char* maps   = (unsigned char*)w;    w += maps_bytes;
        int*           exits  = (int*)w;

        crf_forward_states<<<CRF_B, 1024, 0, stream>>>(em, trans, states);
        crf_bp_matrix<<<CRF_B * NSEG, 1024, 0, stream>>>(states, trans, bp);
        crf_seg_maps<<<CRF_B * NSEG, 256, 0, stream>>>(bp, maps);
        crf_compose<<<CRF_B, 256, 0, stream>>>(states, maps, exits, out);
        crf_emit<<<CRF_B * NSEG, 256, 0, stream>>>(bp, exits, out);
    } else if (ws_size >= states_bytes + bp_bytes) {
        float*         states = (float*)d_ws;
        unsigned char* bp     = (unsigned char*)((char*)d_ws + states_bytes);
        crf_forward_states<<<CRF_B, 1024, 0, stream>>>(em, trans, states);
        crf_bp_matrix<<<CRF_B * NSEG, 1024, 0, stream>>>(states, trans, bp);
        crf_backtrack<<<CRF_B, 256, 0, stream>>>(states, bp, out);
    } else if (ws_size >= states_bytes + tt_bytes) {
        float* states = (float*)d_ws;
        float* Tt     = (float*)((char*)d_ws + states_bytes);
        crf_transpose_trans<<<CRF_K, CRF_K, 0, stream>>>(trans, Tt);
        crf_forward_states<<<CRF_B, 1024, 0, stream>>>(em, trans, states);
        crf_backtrack_states<<<CRF_B, 64, 0, stream>>>(states, Tt, out);
    } else {
        crf_zero_out<<<(out_size + 255) / 256, 256, 0, stream>>>(out, out_size);
    }
}